// Round 2
// baseline (173.297 us; speedup 1.0000x reference)
//
#include <hip/hip_runtime.h>
#include <hip/hip_bf16.h>
#include <stdint.h>

typedef unsigned short u16;
typedef signed char i8;

#define D_INNER 2048
#define D_OUTER 2048
#define MROWS   8192                 // B*S = 2*4096
#define W_ELEMS (D_OUTER * D_INNER)  // 4194304
#define NPART   1024                 // absmean partial blocks (each covers 1024 float4)

// ---- gemm geometry: 256x256 tile, BK=64 i8, 4-slot LDS ring, counted vmcnt ----
#define BM 256
#define BN 256
#define BK 64
#define NKT (D_INNER / BK)           // 32 K-tiles
#define SLOT_BYTES 32768             // A 16KB + B 16KB per slot
#define LDS_TOTAL  131072            // 4 slots

typedef __attribute__((ext_vector_type(4))) float f32x4;
typedef __attribute__((ext_vector_type(4))) int   i32x4;
typedef __attribute__((ext_vector_type(16))) int  i32x16;

// ------- 1) fused prep: blocks [0,8192) = RMSNorm rows -> i8 + per-row step;
//            blocks [8192,8192+1024) = |w| partials  (UNCHANGED this round)
__global__ __launch_bounds__(256) void prep_kernel(const float* __restrict__ x,
                            const float* __restrict__ g,
                            const float* __restrict__ w,
                            i8* __restrict__ xn, float* __restrict__ srow,
                            float* __restrict__ partials) {
  __shared__ float red[4];
  __shared__ float redm[4];
  int t = threadIdx.x;
  int lane = t & 63, wvi = t >> 6;

  if (blockIdx.x >= MROWS) {
    int p = blockIdx.x - MROWS;                    // 0..1023
    int base = p * 1024;
    float s = 0.f;
#pragma unroll
    for (int r = 0; r < 4; ++r) {
      f32x4 v = ((const f32x4*)w)[base + r * 256 + t];
      s += fabsf(v[0]) + fabsf(v[1]) + fabsf(v[2]) + fabsf(v[3]);
    }
    for (int off = 32; off; off >>= 1) s += __shfl_down(s, off, 64);
    if (lane == 0) red[wvi] = s;
    __syncthreads();
    if (t == 0) partials[p] = red[0] + red[1] + red[2] + red[3];
    return;
  }

  int row = blockIdx.x;
  const f32x4* xr = (const f32x4*)(x + (size_t)row * D_INNER);
  i8* xo = xn + (size_t)row * D_INNER;

  f32x4 v0 = __builtin_nontemporal_load(&xr[t]);
  f32x4 v1 = __builtin_nontemporal_load(&xr[t + 256]);
  const f32x4* gr = (const f32x4*)g;
  f32x4 g0 = gr[t], g1 = gr[t + 256];

  float s = v0[0]*v0[0] + v0[1]*v0[1] + v0[2]*v0[2] + v0[3]*v0[3]
          + v1[0]*v1[0] + v1[1]*v1[1] + v1[2]*v1[2] + v1[3]*v1[3];
  float m = fmaxf(fmaxf(fmaxf(fabsf(v0[0]*g0[0]), fabsf(v0[1]*g0[1])),
                        fmaxf(fabsf(v0[2]*g0[2]), fabsf(v0[3]*g0[3]))),
                  fmaxf(fmaxf(fabsf(v1[0]*g1[0]), fabsf(v1[1]*g1[1])),
                        fmaxf(fabsf(v1[2]*g1[2]), fabsf(v1[3]*g1[3]))));
  for (int off = 32; off; off >>= 1) {
    s += __shfl_down(s, off, 64);
    m = fmaxf(m, __shfl_down(m, off, 64));
  }
  if (lane == 0) { red[wvi] = s; redm[wvi] = m; }
  __syncthreads();
  float total = red[0] + red[1] + red[2] + red[3];
  float rmax  = fmaxf(fmaxf(redm[0], redm[1]), fmaxf(redm[2], redm[3]));
  float invr = 1.0f / sqrtf(total * (1.0f / (float)D_INNER) + 1e-6f);

  float amax = fmaxf(rmax * invr, 1e-12f);
  float step = amax * (1.0f / 127.0f);
  float qs   = 127.0f / amax;
  if (t == 0) srow[row] = step;

  char4 q0, q1;
  float qv;
  qv = fminf(127.f, fmaxf(-127.f, rintf(v0[0]*invr*g0[0]*qs))); q0.x = (i8)(int)qv;
  qv = fminf(127.f, fmaxf(-127.f, rintf(v0[1]*invr*g0[1]*qs))); q0.y = (i8)(int)qv;
  qv = fminf(127.f, fmaxf(-127.f, rintf(v0[2]*invr*g0[2]*qs))); q0.z = (i8)(int)qv;
  qv = fminf(127.f, fmaxf(-127.f, rintf(v0[3]*invr*g0[3]*qs))); q0.w = (i8)(int)qv;
  qv = fminf(127.f, fmaxf(-127.f, rintf(v1[0]*invr*g1[0]*qs))); q1.x = (i8)(int)qv;
  qv = fminf(127.f, fmaxf(-127.f, rintf(v1[1]*invr*g1[1]*qs))); q1.y = (i8)(int)qv;
  qv = fminf(127.f, fmaxf(-127.f, rintf(v1[2]*invr*g1[2]*qs))); q1.z = (i8)(int)qv;
  qv = fminf(127.f, fmaxf(-127.f, rintf(v1[3]*invr*g1[3]*qs))); q1.w = (i8)(int)qv;
  ((char4*)xo)[t]       = q0;
  ((char4*)xo)[t + 256] = q1;
}

// ------- 2) ternary quantize -> i8; block0 publishes gamma (UNCHANGED) -------
__global__ __launch_bounds__(256) void quant_kernel(const float* __restrict__ w,
                             const float* __restrict__ partials,
                             float* __restrict__ gamma_out, i8* __restrict__ wq) {
  f32x4 pv = ((const f32x4*)partials)[threadIdx.x];
  double d = (double)pv[0] + (double)pv[1] + (double)pv[2] + (double)pv[3];
  for (int off = 32; off; off >>= 1) d += __shfl_down(d, off, 64);
  __shared__ double red[4];
  int lane = threadIdx.x & 63, wvi = threadIdx.x >> 6;
  if (lane == 0) red[wvi] = d;
  __syncthreads();
  double total = red[0] + red[1] + red[2] + red[3];
  float gamma = (float)(total * (1.0 / (double)W_ELEMS));
  float inv = 1.0f / (gamma + 1e-8f);
  if (blockIdx.x == 0 && threadIdx.x == 0) *gamma_out = gamma;

  int tid = blockIdx.x * blockDim.x + threadIdx.x;
  int stride = gridDim.x * blockDim.x;
  for (int i = tid; i < W_ELEMS / 4; i += stride) {
    f32x4 v = ((const f32x4*)w)[i];
    char4 q;
    q.x = (i8)(int)fminf(1.f, fmaxf(-1.f, rintf(v[0] * inv)));
    q.y = (i8)(int)fminf(1.f, fmaxf(-1.f, rintf(v[1] * inv)));
    q.z = (i8)(int)fminf(1.f, fmaxf(-1.f, rintf(v[2] * inv)));
    q.w = (i8)(int)fminf(1.f, fmaxf(-1.f, rintf(v[3] * inv)));
    ((char4*)wq)[i] = q;
  }
}

// ------- 3) i8 GEMM, pipelined ring: C = (qA * Wq^T) * gamma * step_row -------
// Identical geometry to round 1 (256x256, 8 waves, mfma_i32_32x32x32_i8,
// 4-slot ring, permuted-linear LDS, depth-3 prefetch). ONE change: sync
// primitives follow the verified m201 pattern -- clobber-free bare-asm
// counted vmcnt + raw s_barrier builtin + sched_barrier(0) fences. The
// previous round's `::: "memory"` clobbers made SIInsertWaitcnts emit its
// own vmcnt(0) before each asm, draining the whole ring every tile
// (drain-0 degeneration -> m97-level 53us).
#define GLDS(SRC, DST) __builtin_amdgcn_global_load_lds( \
    (const __attribute__((address_space(1))) void*)(SRC), \
    (__attribute__((address_space(3))) void*)(DST), 16, 0, 0)
#define WAITVM(N) asm volatile("s_waitcnt vmcnt(" #N ")")   // no clobber!
#define BAR()     __builtin_amdgcn_s_barrier()
#define FENCE()   __builtin_amdgcn_sched_barrier(0)

__global__ __launch_bounds__(512, 2) void gemm_bt(const i8* __restrict__ A,
                                                  const i8* __restrict__ Bw,
                                                  const float* __restrict__ gamma_p,
                                                  const float* __restrict__ srow,
                                                  float* __restrict__ C) {
  extern __shared__ i8 lds[];   // 4 * 32KB

  // XCD-chunked swizzle: A panel shared by 8 same-XCD blocks (L2-resident).
  int f   = blockIdx.y * 8 + blockIdx.x;   // 0..255, x-fastest
  int xcd = f & 7;
  int g   = f >> 3;                        // 0..31
  int orig = xcd * 32 + g;
  int nb  = orig & 7;                      // 0..7
  int mb  = orig >> 3;                     // 0..31
  int bm0 = mb * BM;
  int bn0 = nb * BN;

  int tid  = threadIdx.x;
  int lane = tid & 63;
  int wv   = tid >> 6;          // 0..7
  int wr   = wv >> 2;           // 0..1  -> row base wr*128
  int wc   = wv & 3;            // 0..3  -> col base wc*64
  int l31  = lane & 31;
  int hi   = lane >> 5;         // k-group (16 i8 each)
  int wr4  = wr * 4;
  int wc2  = wc * 2;

  const i8* Ag = A  + (size_t)bm0 * D_INNER;
  const i8* Bg = Bw + (size_t)bn0 * D_INNER;

  // per-thread staging decode: LDS chunk tid*16 pulls the global bytes that
  // fragment-read order expects at that chunk (pre-permuted source address).
  int srow_ = ((tid >> 6) & 7) * 32 + (tid & 31);
  int sg_   = (tid >> 5) & 1;
  size_t off0 = (size_t)srow_ * D_INNER + sg_ * 16;
  int dst0 = tid * 16;

  int rdoff = (hi * 32 + l31) * 16;   // lane offset within a fragment group

  i32x16 acc[4][2] = {};

#define STAGE(T_, S_) do { \
    const i8* ap_ = Ag + (size_t)(T_) * BK + off0; \
    const i8* bp_ = Bg + (size_t)(T_) * BK + off0; \
    i8* sa_ = lds + (S_) * SLOT_BYTES + dst0; \
    GLDS(ap_,      sa_);          \
    GLDS(ap_ + 32, sa_ + 8192);   \
    GLDS(bp_,      sa_ + 16384);  \
    GLDS(bp_ + 32, sa_ + 24576);  \
  } while (0)

#define TILE_COMPUTE(T_) do { \
    const i8* sl_ = lds + ((T_) & 3) * SLOT_BYTES; \
    i32x4 af[2][4], bf[2][2]; \
    _Pragma("unroll") for (int ks = 0; ks < 2; ++ks) { \
      _Pragma("unroll") for (int mi = 0; mi < 4; ++mi) \
        af[ks][mi] = *(const i32x4*)(sl_ + ks * 8192 + (wr4 + mi) * 1024 + rdoff); \
      _Pragma("unroll") for (int nj = 0; nj < 2; ++nj) \
        bf[ks][nj] = *(const i32x4*)(sl_ + 16384 + ks * 8192 + (wc2 + nj) * 1024 + rdoff); \
    } \
    __builtin_amdgcn_s_setprio(1); \
    _Pragma("unroll") for (int ks = 0; ks < 2; ++ks) \
      _Pragma("unroll") for (int mi = 0; mi < 4; ++mi) \
        _Pragma("unroll") for (int nj = 0; nj < 2; ++nj) \
          acc[mi][nj] = __builtin_amdgcn_mfma_i32_32x32x32_i8(af[ks][mi], bf[ks][nj], acc[mi][nj], 0, 0, 0); \
    __builtin_amdgcn_s_setprio(0); \
  } while (0)

  STAGE(0, 0); STAGE(1, 1); STAGE(2, 2);

  for (int t = 0; t < NKT - 3; ++t) {
    STAGE(t + 3, (t + 3) & 3);   // issue first: counted by the wait below
    WAITVM(12);                  // oldest 4 loads (tile t, this wave) landed
    BAR();                       // join: all waves' tile-t portions in LDS
    FENCE();                     // ds_reads of tile t must not hoist above
    TILE_COMPUTE(t);
    FENCE();                     // reads complete before next iter's STAGE
    BAR();                       // slot (t+1+3)&3 == (t&3) free for overwrite
  }
  WAITVM(8); BAR(); FENCE(); TILE_COMPUTE(NKT - 3); FENCE(); BAR();
  WAITVM(4); BAR(); FENCE(); TILE_COMPUTE(NKT - 2); FENCE(); BAR();
  WAITVM(0); BAR(); FENCE(); TILE_COMPUTE(NKT - 1);

  // epilogue: C/D 32x32 layout: col = lane&31, row = (reg&3) + 8*(reg>>2) + 4*hi
  float gamma = *gamma_p;
  int colb = bn0 + wc * 64 + l31;
#pragma unroll
  for (int mi = 0; mi < 4; ++mi) {
    int rbase = bm0 + wr * 128 + mi * 32 + hi * 4;
    f32x4 sg[4];
#pragma unroll
    for (int q = 0; q < 4; ++q) {
      f32x4 sv = *(const f32x4*)(srow + rbase + q * 8);
      sg[q] = sv * gamma;
    }
#pragma unroll
    for (int nj = 0; nj < 2; ++nj) {
      i32x16 v = acc[mi][nj];
      float* cp = C + (size_t)rbase * D_OUTER + (colb + nj * 32);
#pragma unroll
      for (int q = 0; q < 4; ++q)
#pragma unroll
        for (int rr = 0; rr < 4; ++rr)
          cp[(size_t)(q * 8 + rr) * D_OUTER] = (float)v[q * 4 + rr] * sg[q][rr];
    }
  }
}

extern "C" void kernel_launch(void* const* d_in, const int* in_sizes, int n_in,
                              void* d_out, int out_size, void* d_ws, size_t ws_size,
                              hipStream_t stream) {
  const float* x = (const float*)d_in[0];   // [2,4096,2048]
  const float* w = (const float*)d_in[1];   // [2048,2048]
  const float* g = (const float*)d_in[2];   // [2048]
  float* out = (float*)d_out;               // [2,4096,2048] fp32

  float* gamma_p  = (float*)d_ws;                                  // 1 float
  float* partials = (float*)((char*)d_ws + 64);                    // 1024 floats
  float* srow     = (float*)((char*)d_ws + 8192);                  // 8192 floats
  i8* xn = (i8*)((char*)d_ws + 8192 + 32768);                      // 16 MB
  i8* wq = (i8*)((char*)d_ws + 8192 + 32768 + (size_t)MROWS * D_INNER);  // 4 MB

  static bool attr_set = false;
  if (!attr_set) {
    (void)hipFuncSetAttribute(reinterpret_cast<const void*>(&gemm_bt),
                              hipFuncAttributeMaxDynamicSharedMemorySize, LDS_TOTAL);
    attr_set = true;
  }

  prep_kernel<<<MROWS + NPART, 256, 0, stream>>>(x, g, w, xn, srow, partials);
  quant_kernel<<<2048, 256, 0, stream>>>(w, partials, gamma_p, wq);
  gemm_bt<<<dim3(8, 32), 512, LDS_TOTAL, stream>>>(xn, wq, gamma_p, srow, out);
}

// Round 3
// 162.719 us; speedup vs baseline: 1.0650x; 1.0650x over previous
//
#include <hip/hip_runtime.h>
#include <hip/hip_bf16.h>
#include <stdint.h>

typedef unsigned short u16;
typedef signed char i8;

#define D_INNER 2048
#define D_OUTER 2048
#define MROWS   8192                 // B*S = 2*4096
#define W_ELEMS (D_OUTER * D_INNER)  // 4194304
#define NPART   1024                 // absmean partial blocks

// ---- gemm geometry: m201-style 8-phase, 256x256 tile, BK=128 i8 ----
#define BM 256
#define BN 256
#define BK 128
#define NKT (D_INNER / BK)           // 16 K-tiles, 2 per iter, 8 iters
#define SLOT_BYTES 65536             // A 32KB + B 32KB per slot
#define LDS_TOTAL  131072            // 2 slots

typedef __attribute__((ext_vector_type(4))) float f32x4;
typedef __attribute__((ext_vector_type(4))) int   i32x4;
typedef __attribute__((ext_vector_type(16))) int  i32x16;

// ------- 1) fused prep (UNCHANGED): RMSNorm rows -> i8 + |w| partials -------
__global__ __launch_bounds__(256) void prep_kernel(const float* __restrict__ x,
                            const float* __restrict__ g,
                            const float* __restrict__ w,
                            i8* __restrict__ xn, float* __restrict__ srow,
                            float* __restrict__ partials) {
  __shared__ float red[4];
  __shared__ float redm[4];
  int t = threadIdx.x;
  int lane = t & 63, wvi = t >> 6;

  if (blockIdx.x >= MROWS) {
    int p = blockIdx.x - MROWS;
    int base = p * 1024;
    float s = 0.f;
#pragma unroll
    for (int r = 0; r < 4; ++r) {
      f32x4 v = ((const f32x4*)w)[base + r * 256 + t];
      s += fabsf(v[0]) + fabsf(v[1]) + fabsf(v[2]) + fabsf(v[3]);
    }
    for (int off = 32; off; off >>= 1) s += __shfl_down(s, off, 64);
    if (lane == 0) red[wvi] = s;
    __syncthreads();
    if (t == 0) partials[p] = red[0] + red[1] + red[2] + red[3];
    return;
  }

  int row = blockIdx.x;
  const f32x4* xr = (const f32x4*)(x + (size_t)row * D_INNER);
  i8* xo = xn + (size_t)row * D_INNER;

  f32x4 v0 = __builtin_nontemporal_load(&xr[t]);
  f32x4 v1 = __builtin_nontemporal_load(&xr[t + 256]);
  const f32x4* gr = (const f32x4*)g;
  f32x4 g0 = gr[t], g1 = gr[t + 256];

  float s = v0[0]*v0[0] + v0[1]*v0[1] + v0[2]*v0[2] + v0[3]*v0[3]
          + v1[0]*v1[0] + v1[1]*v1[1] + v1[2]*v1[2] + v1[3]*v1[3];
  float m = fmaxf(fmaxf(fmaxf(fabsf(v0[0]*g0[0]), fabsf(v0[1]*g0[1])),
                        fmaxf(fabsf(v0[2]*g0[2]), fabsf(v0[3]*g0[3]))),
                  fmaxf(fmaxf(fabsf(v1[0]*g1[0]), fabsf(v1[1]*g1[1])),
                        fmaxf(fabsf(v1[2]*g1[2]), fabsf(v1[3]*g1[3]))));
  for (int off = 32; off; off >>= 1) {
    s += __shfl_down(s, off, 64);
    m = fmaxf(m, __shfl_down(m, off, 64));
  }
  if (lane == 0) { red[wvi] = s; redm[wvi] = m; }
  __syncthreads();
  float total = red[0] + red[1] + red[2] + red[3];
  float rmax  = fmaxf(fmaxf(redm[0], redm[1]), fmaxf(redm[2], redm[3]));
  float invr = 1.0f / sqrtf(total * (1.0f / (float)D_INNER) + 1e-6f);

  float amax = fmaxf(rmax * invr, 1e-12f);
  float step = amax * (1.0f / 127.0f);
  float qs   = 127.0f / amax;
  if (t == 0) srow[row] = step;

  char4 q0, q1;
  float qv;
  qv = fminf(127.f, fmaxf(-127.f, rintf(v0[0]*invr*g0[0]*qs))); q0.x = (i8)(int)qv;
  qv = fminf(127.f, fmaxf(-127.f, rintf(v0[1]*invr*g0[1]*qs))); q0.y = (i8)(int)qv;
  qv = fminf(127.f, fmaxf(-127.f, rintf(v0[2]*invr*g0[2]*qs))); q0.z = (i8)(int)qv;
  qv = fminf(127.f, fmaxf(-127.f, rintf(v0[3]*invr*g0[3]*qs))); q0.w = (i8)(int)qv;
  qv = fminf(127.f, fmaxf(-127.f, rintf(v1[0]*invr*g1[0]*qs))); q1.x = (i8)(int)qv;
  qv = fminf(127.f, fmaxf(-127.f, rintf(v1[1]*invr*g1[1]*qs))); q1.y = (i8)(int)qv;
  qv = fminf(127.f, fmaxf(-127.f, rintf(v1[2]*invr*g1[2]*qs))); q1.z = (i8)(int)qv;
  qv = fminf(127.f, fmaxf(-127.f, rintf(v1[3]*invr*g1[3]*qs))); q1.w = (i8)(int)qv;
  ((char4*)xo)[t]       = q0;
  ((char4*)xo)[t + 256] = q1;
}

// ------- 2) ternary quantize (UNCHANGED) -------
__global__ __launch_bounds__(256) void quant_kernel(const float* __restrict__ w,
                             const float* __restrict__ partials,
                             float* __restrict__ gamma_out, i8* __restrict__ wq) {
  f32x4 pv = ((const f32x4*)partials)[threadIdx.x];
  double d = (double)pv[0] + (double)pv[1] + (double)pv[2] + (double)pv[3];
  for (int off = 32; off; off >>= 1) d += __shfl_down(d, off, 64);
  __shared__ double red[4];
  int lane = threadIdx.x & 63, wvi = threadIdx.x >> 6;
  if (lane == 0) red[wvi] = d;
  __syncthreads();
  double total = red[0] + red[1] + red[2] + red[3];
  float gamma = (float)(total * (1.0 / (double)W_ELEMS));
  float inv = 1.0f / (gamma + 1e-8f);
  if (blockIdx.x == 0 && threadIdx.x == 0) *gamma_out = gamma;

  int tid = blockIdx.x * blockDim.x + threadIdx.x;
  int stride = gridDim.x * blockDim.x;
  for (int i = tid; i < W_ELEMS / 4; i += stride) {
    f32x4 v = ((const f32x4*)w)[i];
    char4 q;
    q.x = (i8)(int)fminf(1.f, fmaxf(-1.f, rintf(v[0] * inv)));
    q.y = (i8)(int)fminf(1.f, fmaxf(-1.f, rintf(v[1] * inv)));
    q.z = (i8)(int)fminf(1.f, fmaxf(-1.f, rintf(v[2] * inv)));
    q.w = (i8)(int)fminf(1.f, fmaxf(-1.f, rintf(v[3] * inv)));
    ((char4*)wq)[i] = q;
  }
}

// ------- 3) i8 GEMM, m201-style 8-phase schedule -------
// 256x256, 8 waves (2Mx4N), per-wave 128x64 out via mfma_i32_32x32x32_i8.
// 2 LDS slots (A 32KB + B 32KB each). LDS row-major [256 rows][128B] with
// XOR-involution: LDS[row][c*16] holds global[row][(c^(row&7))*16]; reads
// use matching XOR -> conflict-free (round-0's measured-0 pattern) AND each
// global_load_lds covers 8 rows x 128B contiguous (coalesced).
// Phase = one mi-strip (32 rows) x full K=128: 8 MFMA. B fragments for the
// whole tile are register-held from tile-phase 0. Region rotation: A-part m
// dead after phase m, all B dead after phase 0 -> stage at phase p writes
// part (p-1) of tile+2 into the live slot, race-free.
// vmcnt(8) only at tile starts (4 phases = 1 full tile in flight); peeled
// final iter uses vmcnt(0) for tail enforcement.
#define GLDS(SRC, DST) __builtin_amdgcn_global_load_lds( \
    (const __attribute__((address_space(1))) void*)(SRC), \
    (__attribute__((address_space(3))) void*)(DST), 16, 0, 0)
#define WAITVM(N) asm volatile("s_waitcnt vmcnt(" #N ")")
#define BAR()     __builtin_amdgcn_s_barrier()
#define FENCE()   __builtin_amdgcn_sched_barrier(0)
#define LGKM0()   do { asm volatile("s_waitcnt lgkmcnt(0)"); FENCE(); } while (0)

__global__ __launch_bounds__(512, 2) void gemm_bt(const i8* __restrict__ A,
                                                  const i8* __restrict__ Bw,
                                                  const float* __restrict__ gamma_p,
                                                  const float* __restrict__ srow,
                                                  float* __restrict__ C) {
  extern __shared__ i8 lds[];   // slot s: A at s*65536, B at s*65536+32768

  int f   = blockIdx.y * 8 + blockIdx.x;   // 0..255, x-fastest
  int xcd = f & 7;
  int gg  = f >> 3;
  int orig = xcd * 32 + gg;
  int nb  = orig & 7;
  int mb  = orig >> 3;
  int bm0 = mb * BM;
  int bn0 = nb * BN;

  int tid  = threadIdx.x;
  int lane = tid & 63;
  int wv   = tid >> 6;          // 0..7
  int wr   = wv >> 2;           // 0..1 -> rows wr*128
  int wc   = wv & 3;            // 0..3 -> cols wc*64
  int l31  = lane & 31;
  int hi   = lane >> 5;

  const i8* Ag = A  + (size_t)bm0 * D_INNER;
  const i8* Bg = Bw + (size_t)bn0 * D_INNER;

  // staging decode: A-part P = rows {P*32..+32} u {128+P*32..+32} (8KB);
  // B-part P = rows {P*64..+64} (8KB). Dest linear in tid; src XOR-permuted.
  int s_arow = (tid >> 8) * 128 + ((tid & 255) >> 3);   // + P*32
  int s_adst = (tid >> 8) * 16384 + (tid & 255) * 16;   // + P*4096 (+slot)
  int s_brow = tid >> 3;                                // + P*64
  int s_chunk = tid & 7;

  // read addressing
  int rbyteA = (wr * 128 + l31) * 128;                  // + tph*4096 + swz
  int rbyteB[2];
  rbyteB[0] = (wc * 64 + l31) * 128;
  rbyteB[1] = (wc * 64 + 32 + l31) * 128;
  int swz[4];
#pragma unroll
  for (int ks = 0; ks < 4; ++ks)
    swz[ks] = (((ks << 1) | hi) ^ (l31 & 7)) << 4;

  i32x16 acc[4][2] = {};
  i32x4 bfr[4][2];

#define STAGE_AB(T_, P_, S_) do { \
    int ar_ = (P_) * 32 + s_arow; \
    GLDS(Ag + (size_t)ar_ * D_INNER + (T_) * BK + ((s_chunk ^ (ar_ & 7)) << 4), \
         lds + (S_) * SLOT_BYTES + (P_) * 4096 + s_adst); \
    int br_ = (P_) * 64 + s_brow; \
    GLDS(Bg + (size_t)br_ * D_INNER + (T_) * BK + ((s_chunk ^ (br_ & 7)) << 4), \
         lds + (S_) * SLOT_BYTES + 32768 + (P_) * 8192 + tid * 16); \
  } while (0)

#define MFMA8(TPH) do { \
    __builtin_amdgcn_s_setprio(1); \
    _Pragma("unroll") for (int ks = 0; ks < 4; ++ks) \
      _Pragma("unroll") for (int nj = 0; nj < 2; ++nj) \
        acc[(TPH)][nj] = __builtin_amdgcn_mfma_i32_32x32x32_i8( \
            af_[ks], bfr[ks][nj], acc[(TPH)][nj], 0, 0, 0); \
    __builtin_amdgcn_s_setprio(0); \
  } while (0)

// tile-phase 0 (PP = 0 or 4): publish tile (wait+bar) BEFORE its reads.
// DS_: 1 = issue stage, 0 = skip (peeled tail).
#define PHASE0(IT, PP, WAITSTMT, DS_) do { \
    if (DS_) { int T_ = ((PP) == 0) ? (2 * (IT) + 1) : (2 * (IT) + 2 + ((((PP)-1) & 7) >> 2)); \
               STAGE_AB(T_, (((PP)-1) & 3), ((((PP)-1) & 7) >> 2)); } \
    WAITSTMT; \
    BAR(); \
    const i8* sb_ = lds + ((PP) >> 2) * SLOT_BYTES; \
    i32x4 af_[4]; \
    _Pragma("unroll") for (int ks = 0; ks < 4; ++ks) \
      af_[ks] = *(const i32x4*)(sb_ + rbyteA + swz[ks]); \
    _Pragma("unroll") for (int ks = 0; ks < 4; ++ks) \
      _Pragma("unroll") for (int nj = 0; nj < 2; ++nj) \
        bfr[ks][nj] = *(const i32x4*)(sb_ + 32768 + rbyteB[nj] + swz[ks]); \
    LGKM0(); \
    MFMA8(0); \
    BAR(); \
  } while (0)

// tile-phases 1..3: reads pre-barrier (data published at tile start).
#define PHASEK(IT, PP, DS_) do { \
    const i8* sb_ = lds + ((PP) >> 2) * SLOT_BYTES; \
    i32x4 af_[4]; \
    _Pragma("unroll") for (int ks = 0; ks < 4; ++ks) \
      af_[ks] = *(const i32x4*)(sb_ + rbyteA + ((PP) & 3) * 4096 + swz[ks]); \
    if (DS_) { int T_ = 2 * (IT) + 2 + ((((PP)-1) & 7) >> 2); \
               STAGE_AB(T_, (((PP)-1) & 3), ((((PP)-1) & 7) >> 2)); } \
    BAR(); \
    LGKM0(); \
    MFMA8((PP) & 3); \
    BAR(); \
  } while (0)

  // prologue: tile0 fully + tile1 parts 0-2 (14 loads/thread)
  STAGE_AB(0, 0, 0); STAGE_AB(0, 1, 0); STAGE_AB(0, 2, 0); STAGE_AB(0, 3, 0);
  STAGE_AB(1, 0, 1); STAGE_AB(1, 1, 1); STAGE_AB(1, 2, 1);

  for (int it = 0; it < 7; ++it) {
    PHASE0(it, 0, WAITVM(8), 1);
    PHASEK(it, 1, 1);
    PHASEK(it, 2, 1);
    PHASEK(it, 3, 1);
    PHASE0(it, 4, WAITVM(8), 1);
    PHASEK(it, 5, 1);
    PHASEK(it, 6, 1);
    PHASEK(it, 7, 1);
  }
  // peeled it=7: only the p=0 stage (tile 15 part 3) remains in-range
  PHASE0(7, 0, WAITVM(8), 1);
  PHASEK(7, 1, 0);
  PHASEK(7, 2, 0);
  PHASEK(7, 3, 0);
  PHASE0(7, 4, WAITVM(0), 0);
  PHASEK(7, 5, 0);
  PHASEK(7, 6, 0);
  PHASEK(7, 7, 0);

  // epilogue: C/D 32x32 layout: col = lane&31, row = (reg&3) + 8*(reg>>2) + 4*hi
  float gamma = *gamma_p;
  int colb = bn0 + wc * 64 + l31;
#pragma unroll
  for (int mi = 0; mi < 4; ++mi) {
    int rbase = bm0 + wr * 128 + mi * 32 + hi * 4;
    f32x4 sg[4];
#pragma unroll
    for (int q = 0; q < 4; ++q) {
      f32x4 sv = *(const f32x4*)(srow + rbase + q * 8);
      sg[q] = sv * gamma;
    }
#pragma unroll
    for (int nj = 0; nj < 2; ++nj) {
      i32x16 v = acc[mi][nj];
      float* cp = C + (size_t)rbase * D_OUTER + (colb + nj * 32);
#pragma unroll
      for (int q = 0; q < 4; ++q)
#pragma unroll
        for (int rr = 0; rr < 4; ++rr)
          cp[(size_t)(q * 8 + rr) * D_OUTER] = (float)v[q * 4 + rr] * sg[q][rr];
    }
  }
}

extern "C" void kernel_launch(void* const* d_in, const int* in_sizes, int n_in,
                              void* d_out, int out_size, void* d_ws, size_t ws_size,
                              hipStream_t stream) {
  const float* x = (const float*)d_in[0];   // [2,4096,2048]
  const float* w = (const float*)d_in[1];   // [2048,2048]
  const float* g = (const float*)d_in[2];   // [2048]
  float* out = (float*)d_out;               // [2,4096,2048] fp32

  float* gamma_p  = (float*)d_ws;                                  // 1 float
  float* partials = (float*)((char*)d_ws + 64);                    // 1024 floats
  float* srow     = (float*)((char*)d_ws + 8192);                  // 8192 floats
  i8* xn = (i8*)((char*)d_ws + 8192 + 32768);                      // 16 MB
  i8* wq = (i8*)((char*)d_ws + 8192 + 32768 + (size_t)MROWS * D_INNER);  // 4 MB

  static bool attr_set = false;
  if (!attr_set) {
    (void)hipFuncSetAttribute(reinterpret_cast<const void*>(&gemm_bt),
                              hipFuncAttributeMaxDynamicSharedMemorySize, LDS_TOTAL);
    attr_set = true;
  }

  prep_kernel<<<MROWS + NPART, 256, 0, stream>>>(x, g, w, xn, srow, partials);
  quant_kernel<<<2048, 256, 0, stream>>>(w, partials, gamma_p, wq);
  gemm_bt<<<dim3(8, 32), 512, LDS_TOTAL, stream>>>(xn, wq, gamma_p, srow, out);
}